// Round 2
// baseline (108.250 us; speedup 1.0000x reference)
//
#include <hip/hip_runtime.h>

// DelayedXOR SH-SNN forward. One thread per independent (b,h) chain
// (s_g.reshape(B,H) maps (g,j)->h=g*16+j one-to-one; no cross-neuron coupling).
//
// R1 -> R2: VGPR=36 showed the compiler scalarized the prefetch arrays and
// sank global loads onto the serial critical path (~100 cyc/step stall,
// matching 52us). Force a register double-buffer with explicit float4 tiles
// (16 steps = 8 x float4), prefetch tile k+1 before computing tile k.
//
// Correctness: bit-exact fp32 vs numpy reference (absmax 0.0 in R1).
// - fp contract OFF everywhere (no fma fusion)
// - exact expression order ((ag*v + omg*gi) - sf)
// - spike(v-1) == (v > 1.0f) exactly in fp32
// - (1-alpha)*integ as sf*oms: exact since sf in {0,1}
// - sigmoid in double, rounded once to fp32

constexpr int BATCH = 1024;
constexpr int T     = 1024;
constexpr int H     = 32;
// decision_start = max(T - T/4, T/2) = 768; tile 48 of 64 (16 steps/tile)
constexpr int NTILE    = 64;
constexpr int ACC_TILE = 48;

struct XT { float4 q0, q1, q2, q3, q4, q5, q6, q7; };  // 16 timesteps

__device__ __forceinline__ XT load_tile(const float4* __restrict__ p, int i)
{
    XT t;
    t.q0 = p[i+0]; t.q1 = p[i+1]; t.q2 = p[i+2]; t.q3 = p[i+3];
    t.q4 = p[i+4]; t.q5 = p[i+5]; t.q6 = p[i+6]; t.q7 = p[i+7];
    return t;
}

template <bool ACC>
__device__ __forceinline__ void step(float x0, float x1,
                                     float w0, float w1,
                                     float ag, float omg,
                                     float as, float oms,
                                     float& v, float& sf,
                                     float& V, float& Sf,
                                     float& acc)
{
#pragma clang fp contract(off)
    float m0 = x0 * w0;          // independent of state: fills latency slots
    float m1 = x1 * w1;
    float gi = m0 + m1;
    float t2 = omg * gi;
    float t1 = ag * v;           // serial core: mul -> add -> sub
    float u  = t1 + t2;
    v = u - sf;
    sf = (v > 1.0f) ? 1.0f : 0.0f;
    float a2 = sf * oms;         // exact for sf in {0,1}; avoids 2nd vcc read
    float a1 = as * V;
    float a3 = a1 + a2;
    V = a3 - Sf;
    Sf = (V > 1.0f) ? 1.0f : 0.0f;
    if (ACC) acc += Sf;
}

template <bool ACC>
__device__ __forceinline__ void tile16(const XT& t,
                                       float w0, float w1,
                                       float ag, float omg,
                                       float as, float oms,
                                       float& v, float& sf,
                                       float& V, float& Sf,
                                       float& acc)
{
#define STEP2(Q) \
    step<ACC>(Q.x, Q.y, w0, w1, ag, omg, as, oms, v, sf, V, Sf, acc); \
    step<ACC>(Q.z, Q.w, w0, w1, ag, omg, as, oms, v, sf, V, Sf, acc);
    STEP2(t.q0) STEP2(t.q1) STEP2(t.q2) STEP2(t.q3)
    STEP2(t.q4) STEP2(t.q5) STEP2(t.q6) STEP2(t.q7)
#undef STEP2
}

__global__ __launch_bounds__(64) void snn_fwd(
    const float* __restrict__ x,       // [B, T, 2]
    const float* __restrict__ Wg,      // [2, 16, 2] == [h][2]
    const float* __restrict__ tau_m,   // [2, 16] == [h]
    const float* __restrict__ soma,    // [32]
    const float* __restrict__ W_out,   // [1, 32]
    const float* __restrict__ b_out,   // [1]
    float* __restrict__ out)           // [B, 1]
{
#pragma clang fp contract(off)
    const int gtid = blockIdx.x * blockDim.x + threadIdx.x;
    const int h = gtid & (H - 1);
    const int b = gtid >> 5;
    if (b >= BATCH) return;

    const float w0 = Wg[2*h + 0];
    const float w1 = Wg[2*h + 1];
    const float ag  = (float)(1.0 / (1.0 + exp(-(double)tau_m[h])));
    const float omg = 1.0f - ag;
    const float as  = (float)(1.0 / (1.0 + exp(-(double)soma[h])));
    const float oms = 1.0f - as;

    const float4* __restrict__ xrow = (const float4*)(x + (size_t)b * (2 * T));

    float v = 0.f, sf = 0.f, V = 0.f, Sf = 0.f, acc = 0.f;

    XT cur = load_tile(xrow, 0);

    // phase 1: tiles [0, 48) — no accumulation. Prefetch k+1, compute k.
#pragma unroll 2
    for (int k = 0; k < ACC_TILE; ++k) {
        XT nxt = load_tile(xrow, (k + 1) * 8);
        tile16<false>(cur, w0, w1, ag, omg, as, oms, v, sf, V, Sf, acc);
        cur = nxt;
    }
    // phase 2: tiles [48, 63) — accumulate S, still prefetching.
#pragma unroll 2
    for (int k = ACC_TILE; k < NTILE - 1; ++k) {
        XT nxt = load_tile(xrow, (k + 1) * 8);
        tile16<true>(cur, w0, w1, ag, omg, as, oms, v, sf, V, Sf, acc);
        cur = nxt;
    }
    // last tile (63)
    tile16<true>(cur, w0, w1, ag, omg, as, oms, v, sf, V, Sf, acc);

    // out[b] = sum_h acc[h] * W_out[h] + b_out. Lanes 0-31 hold batch b_even,
    // 32-63 hold b_odd; xor-reduce within each 32-lane half.
    float val = acc * W_out[h];
#pragma unroll
    for (int m = 16; m >= 1; m >>= 1)
        val += __shfl_xor(val, m, 64);
    if ((gtid & 31) == 0)
        out[b] = val + b_out[0];
}

extern "C" void kernel_launch(void* const* d_in, const int* in_sizes, int n_in,
                              void* d_out, int out_size, void* d_ws, size_t ws_size,
                              hipStream_t stream)
{
    const float* x     = (const float*)d_in[0];
    const float* Wg    = (const float*)d_in[1];
    const float* tau_m = (const float*)d_in[2];
    const float* soma  = (const float*)d_in[3];
    const float* W_out = (const float*)d_in[4];
    const float* b_out = (const float*)d_in[5];
    float* out = (float*)d_out;

    // 512 blocks x 64 threads = 32768 threads = one (b,h) chain each.
    dim3 grid((BATCH * H) / 64), block(64);
    hipLaunchKernelGGL(snn_fwd, grid, block, 0, stream,
                       x, Wg, tau_m, soma, W_out, b_out, out);
}